// Round 1
// baseline (456.108 us; speedup 1.0000x reference)
//
#include <hip/hip_runtime.h>

// AttentionBlock: B=8, S=2048, D=512, fp32 in/out, bf16 MFMA internally.
// ws layout: WT bf16[3][512][512] | Q bf16[8][2048][512] | K bf16[8][2048][512] | VT bf16[8][512][2048]

typedef __attribute__((ext_vector_type(8))) short bf16x8;
typedef __attribute__((ext_vector_type(4))) float f32x4;

__device__ __forceinline__ short f2bf(float f) {
  union { float f; unsigned u; } v; v.f = f;
  unsigned r = v.u + 0x7fffu + ((v.u >> 16) & 1u);
  return (short)(r >> 16);
}

// ---------------- kernel 0: W transpose + cvt -> WT[w][n][k] bf16 ----------------
__global__ __launch_bounds__(256) void wt_kernel(const float* __restrict__ Wq,
                                                 const float* __restrict__ Wk,
                                                 const float* __restrict__ Wv,
                                                 short* __restrict__ WT) {
  int g = blockIdx.x * 256 + threadIdx.x;  // 3 * 512 * 64 = 98304 threads
  int w = g >> 15;
  int rem = g & 32767;
  int n = rem & 511;
  int k0 = (rem >> 9) << 3;
  const float* W = (w == 0) ? Wq : ((w == 1) ? Wk : Wv);
  bf16x8 o;
#pragma unroll
  for (int j = 0; j < 8; ++j) o[j] = f2bf(W[(k0 + j) * 512 + n]);
  *(bf16x8*)(WT + w * 262144 + n * 512 + k0) = o;
}

// ---------------- kernel 1: fused QKV projection GEMM ----------------
// grid (128, 4, 3): 128x128 output tile, z selects {Q, K, V}. V written transposed.
__global__ __launch_bounds__(256) void proj_kernel(const float* __restrict__ x,
                                                   const short* __restrict__ WT,
                                                   short* __restrict__ Qo,
                                                   short* __restrict__ Ko,
                                                   short* __restrict__ VTo) {
  __shared__ short Af[8 * 64 * 8];    // A frags: [mtile][lane][8]
  __shared__ short Bf[8 * 64 * 8];    // B frags: [ntile][lane][8]
  __shared__ short Tb[128 * 136];     // transpose buffer for z==2

  const int tid = threadIdx.x, wv = tid >> 6, ln = tid & 63;
  const int lane_m = ln & 15, lane_q = ln >> 4;
  const int z = blockIdx.z;
  const int m0 = blockIdx.x * 128, n0 = blockIdx.y * 128;
  const short* WTz = WT + z * 262144;
  const int wm = wv & 1, wn = wv >> 1;

  f32x4 zero4 = {0.f, 0.f, 0.f, 0.f};
  f32x4 acc[4][4];
#pragma unroll
  for (int i = 0; i < 4; ++i)
#pragma unroll
    for (int j = 0; j < 4; ++j) acc[i][j] = zero4;

#pragma unroll 1
  for (int kk = 0; kk < 16; ++kk) {
    const int k0 = kk * 32;
    __syncthreads();
#pragma unroll
    for (int i = 0; i < 2; ++i) {
      const int mt = wv * 2 + i;
      {  // A: x fp32 -> bf16 frag
        const float* src = x + (size_t)(m0 + mt * 16 + lane_m) * 512 + k0 + lane_q * 8;
        f32x4 lo = *(const f32x4*)src;
        f32x4 hi = *(const f32x4*)(src + 4);
        bf16x8 vv;
        vv[0] = f2bf(lo[0]); vv[1] = f2bf(lo[1]); vv[2] = f2bf(lo[2]); vv[3] = f2bf(lo[3]);
        vv[4] = f2bf(hi[0]); vv[5] = f2bf(hi[1]); vv[6] = f2bf(hi[2]); vv[7] = f2bf(hi[3]);
        *(bf16x8*)(Af + (mt * 64 + ln) * 8) = vv;
      }
      {  // B: WT bf16 frag (k-contiguous)
        const short* src = WTz + (n0 + mt * 16 + lane_m) * 512 + k0 + lane_q * 8;
        *(bf16x8*)(Bf + (mt * 64 + ln) * 8) = *(const bf16x8*)src;
      }
    }
    __syncthreads();
    bf16x8 a[4], b[4];
#pragma unroll
    for (int i = 0; i < 4; ++i) a[i] = *(bf16x8*)(Af + ((wm * 4 + i) * 64 + ln) * 8);
#pragma unroll
    for (int j = 0; j < 4; ++j) b[j] = *(bf16x8*)(Bf + ((wn * 4 + j) * 64 + ln) * 8);
#pragma unroll
    for (int i = 0; i < 4; ++i)
#pragma unroll
      for (int j = 0; j < 4; ++j)
        acc[i][j] = __builtin_amdgcn_mfma_f32_16x16x32_bf16(a[i], b[j], acc[i][j], 0, 0, 0);
  }

  if (z < 2) {
    short* O = (z == 0) ? Qo : Ko;
#pragma unroll
    for (int i = 0; i < 4; ++i)
#pragma unroll
      for (int j = 0; j < 4; ++j)
#pragma unroll
        for (int rr = 0; rr < 4; ++rr) {
          int row = m0 + wm * 64 + i * 16 + lane_q * 4 + rr;
          int col = n0 + wn * 64 + j * 16 + lane_m;
          O[(size_t)row * 512 + col] = f2bf(acc[i][j][rr]);
        }
  } else {
    // V: transpose through LDS, store VT[b][d][s]
#pragma unroll
    for (int i = 0; i < 4; ++i)
#pragma unroll
      for (int j = 0; j < 4; ++j)
#pragma unroll
        for (int rr = 0; rr < 4; ++rr) {
          int rl = wm * 64 + i * 16 + lane_q * 4 + rr;
          int cl = wn * 64 + j * 16 + lane_m;
          Tb[cl * 136 + rl] = f2bf(acc[i][j][rr]);
        }
    __syncthreads();
    const int bb = m0 >> 11, s0 = m0 & 2047;
    const int c = tid >> 1, h = tid & 1;
    short* dst = VTo + ((size_t)bb * 512 + n0 + c) * 2048 + s0 + h * 64;
    const short* srcl = Tb + c * 136 + h * 64;
#pragma unroll
    for (int u = 0; u < 8; ++u) *(bf16x8*)(dst + u * 8) = *(const bf16x8*)(srcl + u * 8);
  }
}

// ---------------- kernel 2: flash attention ----------------
// grid (64, 8): 32 Q rows per WG, iterate 32 KV tiles of 64 keys. 4 waves:
// S-phase: wave w owns key-ntile w (full D contraction). PV: wave w owns d-slice w*128.
__global__ __launch_bounds__(256) void flash_kernel(const short* __restrict__ Q,
                                                    const short* __restrict__ K,
                                                    const short* __restrict__ VT,
                                                    float* __restrict__ out) {
  __shared__ short qf[16 * 2 * 64 * 8];  // Q A-frags: [ks][mi][lane][8]
  __shared__ float sbuf[32 * 68];        // S tile fp32 (padded stride)
  __shared__ short pf[2 * 2 * 64 * 8];   // P A-frags: [ks2][mi][lane][8]
  __shared__ float m_s[32], l_s[32], al_s[32];

  const int tid = threadIdx.x, wv = tid >> 6, ln = tid & 63;
  const int lane_m = ln & 15, lane_q = ln >> 4;
  const int b = blockIdx.y, m0 = blockIdx.x * 32;
  const short* Qp = Q + ((size_t)b * 2048 + m0) * 512;
  const short* Kp = K + (size_t)b * 2048 * 512;
  const short* VTp = VT + (size_t)b * 512 * 2048;
  const float scale = 0.044194173824159216f;  // 1/sqrt(512)

  // stage Q into A-frag layout (once)
#pragma unroll
  for (int r = 0; r < 8; ++r) {
    const int region = wv * 8 + r;  // = ks*2 + mi
    const int mi = region & 1, ks = region >> 1;
    const short* src = Qp + (mi * 16 + lane_m) * 512 + ks * 32 + lane_q * 8;
    *(bf16x8*)(qf + (region * 64 + ln) * 8) = *(const bf16x8*)src;
  }
  if (tid < 32) { m_s[tid] = -1e30f; l_s[tid] = 0.f; }

  f32x4 zero4 = {0.f, 0.f, 0.f, 0.f};
  f32x4 O[2][8];
#pragma unroll
  for (int mi = 0; mi < 2; ++mi)
#pragma unroll
    for (int nt = 0; nt < 8; ++nt) O[mi][nt] = zero4;
  __syncthreads();

#pragma unroll 1
  for (int kt = 0; kt < 32; ++kt) {
    const int kb = kt * 64;
    // ---- S = Q K^T (wave w computes key columns w*16..w*16+15, both m-tiles) ----
    f32x4 sacc[2];
    sacc[0] = zero4; sacc[1] = zero4;
#pragma unroll
    for (int ks = 0; ks < 16; ++ks) {
      bf16x8 bfr = *(const bf16x8*)(Kp + (size_t)(kb + wv * 16 + lane_m) * 512 + ks * 32 + lane_q * 8);
      bf16x8 a0 = *(bf16x8*)(qf + ((ks * 2 + 0) * 64 + ln) * 8);
      bf16x8 a1 = *(bf16x8*)(qf + ((ks * 2 + 1) * 64 + ln) * 8);
      sacc[0] = __builtin_amdgcn_mfma_f32_16x16x32_bf16(a0, bfr, sacc[0], 0, 0, 0);
      sacc[1] = __builtin_amdgcn_mfma_f32_16x16x32_bf16(a1, bfr, sacc[1], 0, 0, 0);
    }
#pragma unroll
    for (int mi = 0; mi < 2; ++mi)
#pragma unroll
      for (int rr = 0; rr < 4; ++rr)
        sbuf[(mi * 16 + lane_q * 4 + rr) * 68 + wv * 16 + lane_m] = sacc[mi][rr];
    __syncthreads();  // B1

    // ---- online softmax: thread t -> row t/8, cols (t&7)*8..+7 ----
    {
      const int r = tid >> 3, c0 = (tid & 7) * 8;
      f32x4 v0 = *(f32x4*)(sbuf + r * 68 + c0);
      f32x4 v1 = *(f32x4*)(sbuf + r * 68 + c0 + 4);
      float s8[8] = {v0[0], v0[1], v0[2], v0[3], v1[0], v1[1], v1[2], v1[3]};
      float mx = s8[0];
#pragma unroll
      for (int j = 1; j < 8; ++j) mx = fmaxf(mx, s8[j]);
      mx = fmaxf(mx, __shfl_xor(mx, 1));
      mx = fmaxf(mx, __shfl_xor(mx, 2));
      mx = fmaxf(mx, __shfl_xor(mx, 4));
      float m_old = m_s[r], l_old = l_s[r];
      float m_new = fmaxf(m_old, mx * scale);
      float alpha = __expf(m_old - m_new);
      float p[8], sum = 0.f;
#pragma unroll
      for (int j = 0; j < 8; ++j) { p[j] = __expf(s8[j] * scale - m_new); sum += p[j]; }
      sum += __shfl_xor(sum, 1);
      sum += __shfl_xor(sum, 2);
      sum += __shfl_xor(sum, 4);
      if ((tid & 7) == 0) { m_s[r] = m_new; l_s[r] = l_old * alpha + sum; al_s[r] = alpha; }
      bf16x8 pv;
#pragma unroll
      for (int j = 0; j < 8; ++j) pv[j] = f2bf(p[j]);
      const int kstep = (tid & 7) >> 2, quad = (tid & 7) & 3, mt = r >> 4;
      const int lane_a = (r & 15) + quad * 16;
      *(bf16x8*)(pf + ((kstep * 2 + mt) * 64 + lane_a) * 8) = pv;
    }
    __syncthreads();  // B2

    // ---- rescale O, then O += P V (wave w owns d-slice w*128..+128) ----
    float av[2][4];
#pragma unroll
    for (int mi = 0; mi < 2; ++mi)
#pragma unroll
      for (int rr = 0; rr < 4; ++rr) av[mi][rr] = al_s[mi * 16 + lane_q * 4 + rr];
#pragma unroll
    for (int mi = 0; mi < 2; ++mi)
#pragma unroll
      for (int nt = 0; nt < 8; ++nt)
#pragma unroll
        for (int rr = 0; rr < 4; ++rr) O[mi][nt][rr] *= av[mi][rr];
#pragma unroll
    for (int ks2 = 0; ks2 < 2; ++ks2) {
      bf16x8 a0 = *(bf16x8*)(pf + ((ks2 * 2 + 0) * 64 + ln) * 8);
      bf16x8 a1 = *(bf16x8*)(pf + ((ks2 * 2 + 1) * 64 + ln) * 8);
#pragma unroll
      for (int nt = 0; nt < 8; ++nt) {
        bf16x8 bv = *(const bf16x8*)(VTp + (size_t)(wv * 128 + nt * 16 + lane_m) * 2048 + kb + ks2 * 32 + lane_q * 8);
        O[0][nt] = __builtin_amdgcn_mfma_f32_16x16x32_bf16(a0, bv, O[0][nt], 0, 0, 0);
        O[1][nt] = __builtin_amdgcn_mfma_f32_16x16x32_bf16(a1, bv, O[1][nt], 0, 0, 0);
      }
    }
  }

  // epilogue: O / l
  float linv[2][4];
#pragma unroll
  for (int mi = 0; mi < 2; ++mi)
#pragma unroll
    for (int rr = 0; rr < 4; ++rr) linv[mi][rr] = 1.f / l_s[mi * 16 + lane_q * 4 + rr];
#pragma unroll
  for (int mi = 0; mi < 2; ++mi)
#pragma unroll
    for (int nt = 0; nt < 8; ++nt)
#pragma unroll
      for (int rr = 0; rr < 4; ++rr) {
        size_t row = (size_t)b * 2048 + m0 + mi * 16 + lane_q * 4 + rr;
        out[row * 512 + wv * 128 + nt * 16 + lane_m] = O[mi][nt][rr] * linv[mi][rr];
      }
}

extern "C" void kernel_launch(void* const* d_in, const int* in_sizes, int n_in,
                              void* d_out, int out_size, void* d_ws, size_t ws_size,
                              hipStream_t stream) {
  const float* x  = (const float*)d_in[0];
  const float* Wq = (const float*)d_in[1];
  const float* Wk = (const float*)d_in[2];
  const float* Wv = (const float*)d_in[3];
  float* out = (float*)d_out;
  char* ws = (char*)d_ws;
  short* WT  = (short*)ws;                                   // 1,572,864 B
  short* Qw  = (short*)(ws + 1572864);                       // 16 MB
  short* Kw  = (short*)(ws + 1572864 + 16777216);            // 16 MB
  short* VTw = (short*)(ws + 1572864 + 2 * 16777216);        // 16 MB

  wt_kernel<<<dim3(384), dim3(256), 0, stream>>>(Wq, Wk, Wv, WT);
  proj_kernel<<<dim3(128, 4, 3), dim3(256), 0, stream>>>(x, WT, Qw, Kw, VTw);
  flash_kernel<<<dim3(64, 8), dim3(256), 0, stream>>>(Qw, Kw, VTw, out);
}

// Round 2
// 387.754 us; speedup vs baseline: 1.1763x; 1.1763x over previous
//
#include <hip/hip_runtime.h>

// AttentionBlock: B=8, S=2048, D=512, fp32 in/out, bf16 MFMA internally.
// ws: WT bf16[3][512][512] | Q bf16[8][2048][512] | K bf16[8][2048][512] | VT bf16[8][512][2048] | xb bf16[16384][512]

typedef __attribute__((ext_vector_type(8))) short bf16x8;
typedef __attribute__((ext_vector_type(4))) float f32x4;

__device__ __forceinline__ short f2bf(float f) {
  union { float f; unsigned u; } v; v.f = f;
  unsigned r = v.u + 0x7fffu + ((v.u >> 16) & 1u);
  return (short)(r >> 16);
}

__device__ __forceinline__ void async_cp16(const void* g, void* l) {
  __builtin_amdgcn_global_load_lds(
      (const __attribute__((address_space(1))) unsigned int*)g,
      (__attribute__((address_space(3))) unsigned int*)l, 16, 0, 0);
}

// ---------------- kernel 0: prep = W transpose+cvt  AND  x -> bf16 ----------------
__global__ __launch_bounds__(256) void prep_kernel(const float* __restrict__ x,
                                                   const float* __restrict__ Wq,
                                                   const float* __restrict__ Wk,
                                                   const float* __restrict__ Wv,
                                                   short* __restrict__ WT,
                                                   short* __restrict__ xb) {
  if (blockIdx.x < 384) {
    int g = blockIdx.x * 256 + threadIdx.x;  // 3*512*64
    int w = g >> 15;
    int rem = g & 32767;
    int n = rem & 511;
    int k0 = (rem >> 9) << 3;
    const float* W = (w == 0) ? Wq : ((w == 1) ? Wk : Wv);
    bf16x8 o;
#pragma unroll
    for (int j = 0; j < 8; ++j) o[j] = f2bf(W[(k0 + j) * 512 + n]);
    *(bf16x8*)(WT + w * 262144 + n * 512 + k0) = o;
  } else {
    size_t g = (size_t)(blockIdx.x - 384) * 256 + threadIdx.x;  // 1,048,576 threads x 8 elems
    size_t off = g * 8;
    f32x4 lo = *(const f32x4*)(x + off);
    f32x4 hi = *(const f32x4*)(x + off + 4);
    bf16x8 o;
    o[0] = f2bf(lo[0]); o[1] = f2bf(lo[1]); o[2] = f2bf(lo[2]); o[3] = f2bf(lo[3]);
    o[4] = f2bf(hi[0]); o[5] = f2bf(hi[1]); o[6] = f2bf(hi[2]); o[7] = f2bf(hi[3]);
    *(bf16x8*)(xb + off) = o;
  }
}

// ---------------- kernel 1: fused QKV projection GEMM (m97-style staging) ----------------
// grid (128, 4, 3): 128x128 output tile, z selects {Q, K, V}. V written transposed.
__global__ __launch_bounds__(256) void proj_kernel(const short* __restrict__ xb,
                                                   const short* __restrict__ WT,
                                                   short* __restrict__ Qo,
                                                   short* __restrict__ Ko,
                                                   short* __restrict__ VTo) {
  __shared__ __align__(16) short smem[128 * 136];  // 34.8 KB; Af/Bf during K-loop, Tb in epilogue
  short* Af = smem;           // [mt 0..7][lane][8]
  short* Bf = smem + 4096;    // [nt 0..7][lane][8]
  short* Tb = smem;           // [128][136] epilogue transpose buffer

  const int tid = threadIdx.x, wv = tid >> 6, ln = tid & 63;
  const int lane_m = ln & 15, lane_q = ln >> 4;
  const int z = blockIdx.z;
  const int m0 = blockIdx.x * 128, n0 = blockIdx.y * 128;
  const short* WTz = WT + z * 262144;
  const int wm = wv & 1, wn = wv >> 1;

  f32x4 zero4 = {0.f, 0.f, 0.f, 0.f};
  f32x4 acc[4][4];
#pragma unroll
  for (int i = 0; i < 4; ++i)
#pragma unroll
    for (int j = 0; j < 4; ++j) acc[i][j] = zero4;

#pragma unroll 1
  for (int kk = 0; kk < 16; ++kk) {
    const int k0 = kk * 32;
    __syncthreads();
#pragma unroll
    for (int i = 0; i < 2; ++i) {
      const int mt = wv * 2 + i;
      async_cp16(xb + (size_t)(m0 + mt * 16 + lane_m) * 512 + k0 + lane_q * 8, Af + mt * 512);
      async_cp16(WTz + (n0 + mt * 16 + lane_m) * 512 + k0 + lane_q * 8, Bf + mt * 512);
    }
    __syncthreads();
    bf16x8 a[4], b[4];
#pragma unroll
    for (int i = 0; i < 4; ++i) a[i] = *(bf16x8*)(Af + ((wm * 4 + i) * 64 + ln) * 8);
#pragma unroll
    for (int j = 0; j < 4; ++j) b[j] = *(bf16x8*)(Bf + ((wn * 4 + j) * 64 + ln) * 8);
#pragma unroll
    for (int i = 0; i < 4; ++i)
#pragma unroll
      for (int j = 0; j < 4; ++j)
        acc[i][j] = __builtin_amdgcn_mfma_f32_16x16x32_bf16(a[i], b[j], acc[i][j], 0, 0, 0);
  }
  __syncthreads();  // Af/Bf dead; smem becomes Tb

  if (z < 2) {
    // write C to Tb row-major, then coalesced 16B stores
#pragma unroll
    for (int i = 0; i < 4; ++i)
#pragma unroll
      for (int j = 0; j < 4; ++j)
#pragma unroll
        for (int rr = 0; rr < 4; ++rr)
          Tb[(wm * 64 + i * 16 + lane_q * 4 + rr) * 136 + wn * 64 + j * 16 + lane_m] = f2bf(acc[i][j][rr]);
    __syncthreads();
    short* O = (z == 0) ? Qo : Ko;
    const int r = tid >> 1, h = tid & 1;
    short* dst = O + (size_t)(m0 + r) * 512 + n0 + h * 64;
    const short* srcl = Tb + r * 136 + h * 64;
#pragma unroll
    for (int u = 0; u < 8; ++u) *(bf16x8*)(dst + u * 8) = *(const bf16x8*)(srcl + u * 8);
  } else {
    // V: transpose through LDS, store VT[b][d][s]
#pragma unroll
    for (int i = 0; i < 4; ++i)
#pragma unroll
      for (int j = 0; j < 4; ++j)
#pragma unroll
        for (int rr = 0; rr < 4; ++rr) {
          int rl = wm * 64 + i * 16 + lane_q * 4 + rr;
          int cl = wn * 64 + j * 16 + lane_m;
          Tb[cl * 136 + rl] = f2bf(acc[i][j][rr]);
        }
    __syncthreads();
    const int bb = m0 >> 11, s0 = m0 & 2047;
    const int c = tid >> 1, h = tid & 1;
    short* dst = VTo + ((size_t)bb * 512 + n0 + c) * 2048 + s0 + h * 64;
    const short* srcl = Tb + c * 136 + h * 64;
#pragma unroll
    for (int u = 0; u < 8; ++u) *(bf16x8*)(dst + u * 8) = *(const bf16x8*)(srcl + u * 8);
  }
}

// ---------------- kernel 2: flash attention ----------------
// grid (512): b = blockIdx.x & 7 (batch -> XCD for L2 locality), tile = blockIdx.x >> 3.
// 32 Q rows per WG, 32 KV tiles of 64 keys. S-phase: wave w owns key cols w*16..+15.
// PV: wave w owns d-slice w*128..+127. VT frags prefetched across softmax barriers.
__global__ __launch_bounds__(256) void flash_kernel(const short* __restrict__ Q,
                                                    const short* __restrict__ K,
                                                    const short* __restrict__ VT,
                                                    float* __restrict__ out) {
  __shared__ __align__(16) short qf[16 * 2 * 64 * 8];  // Q A-frags: [ks][mi][lane][8]
  __shared__ float sbuf[32 * 68];                      // S tile (log2-domain scaled)
  __shared__ __align__(16) short pf[2 * 2 * 64 * 8];   // P A-frags (lane-swizzled)
  __shared__ float m_s[32], l_s[32], al_s[32];

  const int tid = threadIdx.x, wv = tid >> 6, ln = tid & 63;
  const int lane_m = ln & 15, lane_q = ln >> 4;
  const int b = blockIdx.x & 7, m0 = (blockIdx.x >> 3) * 32;
  const short* Qp = Q + ((size_t)b * 2048 + m0) * 512;
  const short* Kp = K + (size_t)b * 2048 * 512;
  const short* VTp = VT + (size_t)b * 512 * 2048;
  const float sc2 = 0.044194173824159216f * 1.4426950408889634f;  // 1/sqrt(512) * log2(e)

  // stage Q into A-frag layout (once)
#pragma unroll
  for (int r = 0; r < 8; ++r) {
    const int region = wv * 8 + r;  // = ks*2 + mi
    const int mi = region & 1, ks = region >> 1;
    const short* src = Qp + (mi * 16 + lane_m) * 512 + ks * 32 + lane_q * 8;
    *(bf16x8*)(qf + (region * 64 + ln) * 8) = *(const bf16x8*)src;
  }
  if (tid < 32) { m_s[tid] = -1e30f; l_s[tid] = 0.f; }

  f32x4 zero4 = {0.f, 0.f, 0.f, 0.f};
  f32x4 O[2][8];
#pragma unroll
  for (int mi = 0; mi < 2; ++mi)
#pragma unroll
    for (int nt = 0; nt < 8; ++nt) O[mi][nt] = zero4;
  __syncthreads();

#pragma unroll 1
  for (int kt = 0; kt < 32; ++kt) {
    const int kb = kt * 64;
    // ---- S = Q K^T ----
    f32x4 sacc[2];
    sacc[0] = zero4; sacc[1] = zero4;
#pragma unroll
    for (int ks = 0; ks < 16; ++ks) {
      bf16x8 bfr = *(const bf16x8*)(Kp + (size_t)(kb + wv * 16 + lane_m) * 512 + ks * 32 + lane_q * 8);
      bf16x8 a0 = *(bf16x8*)(qf + ((ks * 2 + 0) * 64 + ln) * 8);
      bf16x8 a1 = *(bf16x8*)(qf + ((ks * 2 + 1) * 64 + ln) * 8);
      sacc[0] = __builtin_amdgcn_mfma_f32_16x16x32_bf16(a0, bfr, sacc[0], 0, 0, 0);
      sacc[1] = __builtin_amdgcn_mfma_f32_16x16x32_bf16(a1, bfr, sacc[1], 0, 0, 0);
    }
    // ---- prefetch VT frags for PV (in flight across the softmax barriers) ----
    bf16x8 bvp0[8], bvp1[8];
#pragma unroll
    for (int nt = 0; nt < 8; ++nt) {
      const short* vb = VTp + (size_t)(wv * 128 + nt * 16 + lane_m) * 2048 + kb + lane_q * 8;
      bvp0[nt] = *(const bf16x8*)vb;
      bvp1[nt] = *(const bf16x8*)(vb + 32);
    }
#pragma unroll
    for (int mi = 0; mi < 2; ++mi)
#pragma unroll
      for (int rr = 0; rr < 4; ++rr)
        sbuf[(mi * 16 + lane_q * 4 + rr) * 68 + wv * 16 + lane_m] = sacc[mi][rr] * sc2;
    __syncthreads();  // B1

    // ---- online softmax (log2 domain): thread t -> row t/8, cols (t&7)*8..+7 ----
    {
      const int r = tid >> 3, c0 = (tid & 7) * 8;
      f32x4 v0 = *(f32x4*)(sbuf + r * 68 + c0);
      f32x4 v1 = *(f32x4*)(sbuf + r * 68 + c0 + 4);
      float s8[8] = {v0[0], v0[1], v0[2], v0[3], v1[0], v1[1], v1[2], v1[3]};
      float mx = s8[0];
#pragma unroll
      for (int j = 1; j < 8; ++j) mx = fmaxf(mx, s8[j]);
      mx = fmaxf(mx, __shfl_xor(mx, 1));
      mx = fmaxf(mx, __shfl_xor(mx, 2));
      mx = fmaxf(mx, __shfl_xor(mx, 4));
      float m_old = m_s[r], l_old = l_s[r];
      float m_new = fmaxf(m_old, mx);
      float alpha = exp2f(m_old - m_new);
      float p[8], sum = 0.f;
#pragma unroll
      for (int j = 0; j < 8; ++j) { p[j] = exp2f(s8[j] - m_new); sum += p[j]; }
      sum += __shfl_xor(sum, 1);
      sum += __shfl_xor(sum, 2);
      sum += __shfl_xor(sum, 4);
      if ((tid & 7) == 0) { m_s[r] = m_new; l_s[r] = l_old * alpha + sum; al_s[r] = alpha; }
      bf16x8 pv;
#pragma unroll
      for (int j = 0; j < 8; ++j) pv[j] = f2bf(p[j]);
      const int kstep = (tid & 7) >> 2, quad = (tid & 7) & 3, mt = r >> 4;
      const int lane_a = (r & 15) + quad * 16;
      const int eff = lane_a ^ (lane_a >> 4);  // bank-conflict swizzle
      *(bf16x8*)(pf + ((kstep * 2 + mt) * 64 + eff) * 8) = pv;
    }
    __syncthreads();  // B2

    // ---- rescale O, then O += P V (wave w owns d-slice w*128..+127) ----
    const int effr = ln ^ (ln >> 4);
    float av[2][4];
#pragma unroll
    for (int mi = 0; mi < 2; ++mi)
#pragma unroll
      for (int rr = 0; rr < 4; ++rr) av[mi][rr] = al_s[mi * 16 + lane_q * 4 + rr];
#pragma unroll
    for (int mi = 0; mi < 2; ++mi)
#pragma unroll
      for (int nt = 0; nt < 8; ++nt)
#pragma unroll
        for (int rr = 0; rr < 4; ++rr) O[mi][nt][rr] *= av[mi][rr];
    {
      bf16x8 a00 = *(bf16x8*)(pf + ((0 * 2 + 0) * 64 + effr) * 8);
      bf16x8 a01 = *(bf16x8*)(pf + ((0 * 2 + 1) * 64 + effr) * 8);
      bf16x8 a10 = *(bf16x8*)(pf + ((1 * 2 + 0) * 64 + effr) * 8);
      bf16x8 a11 = *(bf16x8*)(pf + ((1 * 2 + 1) * 64 + effr) * 8);
#pragma unroll
      for (int nt = 0; nt < 8; ++nt) {
        O[0][nt] = __builtin_amdgcn_mfma_f32_16x16x32_bf16(a00, bvp0[nt], O[0][nt], 0, 0, 0);
        O[1][nt] = __builtin_amdgcn_mfma_f32_16x16x32_bf16(a01, bvp0[nt], O[1][nt], 0, 0, 0);
        O[0][nt] = __builtin_amdgcn_mfma_f32_16x16x32_bf16(a10, bvp1[nt], O[0][nt], 0, 0, 0);
        O[1][nt] = __builtin_amdgcn_mfma_f32_16x16x32_bf16(a11, bvp1[nt], O[1][nt], 0, 0, 0);
      }
    }
  }

  // epilogue: O / l
  float linv[2][4];
#pragma unroll
  for (int mi = 0; mi < 2; ++mi)
#pragma unroll
    for (int rr = 0; rr < 4; ++rr) linv[mi][rr] = 1.f / l_s[mi * 16 + lane_q * 4 + rr];
#pragma unroll
  for (int mi = 0; mi < 2; ++mi)
#pragma unroll
    for (int nt = 0; nt < 8; ++nt)
#pragma unroll
      for (int rr = 0; rr < 4; ++rr) {
        size_t row = (size_t)b * 2048 + m0 + mi * 16 + lane_q * 4 + rr;
        out[row * 512 + wv * 128 + nt * 16 + lane_m] = O[mi][nt][rr] * linv[mi][rr];
      }
}

extern "C" void kernel_launch(void* const* d_in, const int* in_sizes, int n_in,
                              void* d_out, int out_size, void* d_ws, size_t ws_size,
                              hipStream_t stream) {
  const float* x  = (const float*)d_in[0];
  const float* Wq = (const float*)d_in[1];
  const float* Wk = (const float*)d_in[2];
  const float* Wv = (const float*)d_in[3];
  float* out = (float*)d_out;
  char* ws = (char*)d_ws;
  short* WT  = (short*)ws;                                   // 1,572,864 B
  short* Qw  = (short*)(ws + 1572864);                       // 16 MB
  short* Kw  = (short*)(ws + 1572864 + 16777216);            // 16 MB
  short* VTw = (short*)(ws + 1572864 + 2 * 16777216);        // 16 MB
  short* xb  = (short*)(ws + 1572864 + 3 * 16777216);        // 16 MB

  prep_kernel<<<dim3(384 + 4096), dim3(256), 0, stream>>>(x, Wq, Wk, Wv, WT, xb);
  proj_kernel<<<dim3(128, 4, 3), dim3(256), 0, stream>>>(xb, WT, Qw, Kw, VTw);
  flash_kernel<<<dim3(512), dim3(256), 0, stream>>>(Qw, Kw, VTw, out);
}